// Round 11
// baseline (1451.887 us; speedup 1.0000x reference)
//
#include <hip/hip_runtime.h>
#include <hip/hip_bf16.h>

// Problem constants (match reference)
#define NN 100000
#define NG 512
#define H  128

typedef _Float16 half8 __attribute__((ext_vector_type(8)));
typedef _Float16 half2v __attribute__((ext_vector_type(2)));
typedef float f32x4 __attribute__((ext_vector_type(4)));

// ---------------------------------------------------------------------------
// CSR build: histogram of dst
__global__ __launch_bounds__(256) void k_hist(const int* __restrict__ dst,
                                              int* __restrict__ deg, int E) {
    int e = blockIdx.x * 256 + threadIdx.x;
    if (e < E) atomicAdd(&deg[dst[e]], 1);
}

// per-block exclusive scan (256 elems), partial sums to bsum
__global__ __launch_bounds__(256) void k_scan_block(const int* __restrict__ deg,
                                                    int* __restrict__ rowptr,
                                                    int* __restrict__ bsum, int n) {
    __shared__ int s[256];
    int tid = threadIdx.x;
    int i = blockIdx.x * 256 + tid;
    int v = (i < n) ? deg[i] : 0;
    s[tid] = v;
    __syncthreads();
    #pragma unroll
    for (int off = 1; off < 256; off <<= 1) {
        int t = (tid >= off) ? s[tid - off] : 0;
        __syncthreads();
        s[tid] += t;
        __syncthreads();
    }
    if (i < n) rowptr[i] = s[tid] - v;            // exclusive within block
    if (tid == 255) bsum[blockIdx.x] = s[255];    // block total
}

// scan of block sums (nb <= 512), single block
__global__ __launch_bounds__(512) void k_scan_top(int* __restrict__ bsum, int nb) {
    __shared__ int s[512];
    int tid = threadIdx.x;
    int v = (tid < nb) ? bsum[tid] : 0;
    s[tid] = v;
    __syncthreads();
    #pragma unroll
    for (int off = 1; off < 512; off <<= 1) {
        int t = (tid >= off) ? s[tid - off] : 0;
        __syncthreads();
        s[tid] += t;
        __syncthreads();
    }
    if (tid < nb) bsum[tid] = s[tid] - v;         // exclusive
}

// finalize: rowptr += block offset; cursor = rowptr; dinv = rsqrt(deg+1)
__global__ __launch_bounds__(256) void k_scan_fin(int* __restrict__ rowptr,
                                                  const int* __restrict__ bsum,
                                                  const int* __restrict__ deg,
                                                  int* __restrict__ cursor,
                                                  float* __restrict__ dinv,
                                                  int n, int E) {
    int i = blockIdx.x * 256 + threadIdx.x;
    if (i >= n) return;
    int r = rowptr[i] + bsum[i >> 8];
    rowptr[i] = r;
    cursor[i] = r;
    dinv[i] = rsqrtf((float)deg[i] + 1.0f);       // +1 self-loop; always > 0
    if (i == 0) rowptr[n] = E;
}

// ---------------------------------------------------------------------------
// transpose + fp16-convert both weights: Wt[n*128+k] = (half)W[k*128+n]
__global__ __launch_bounds__(256) void k_wprep(const float* __restrict__ W1,
                                               const float* __restrict__ W2,
                                               _Float16* __restrict__ Wt1,
                                               _Float16* __restrict__ Wt2) {
    int bb = blockIdx.x;
    const float* W = (bb < 64) ? W1 : W2;
    _Float16* Wt = (bb < 64) ? Wt1 : Wt2;
    int i = (bb & 63) * 256 + threadIdx.x;        // 0..16383
    int k = i >> 7, n = i & 127;
    Wt[n * 128 + k] = (_Float16)W[i];
}

// ---------------------------------------------------------------------------
// Fused: blocks [0,nfb) fill CSR col; blocks [nfb,..) do GEMM1
// (tS = (x@W1)*dinv[row], fp16 out). LDS-free MFMA GEMM.
// MFMA layouts (verified m89/m120): A[m=l16][k=quad*8+j]; B[n=l16][k=quad*8+j];
// C col=l16, row=quad*4+reg.
__global__ __launch_bounds__(256) void k_fill_gemm1(
        const int* __restrict__ src, const int* __restrict__ dst,
        int* __restrict__ cursor, int* __restrict__ col, int E, int nfb,
        const float* __restrict__ x, const _Float16* __restrict__ Wt1,
        const float* __restrict__ dinv, _Float16* __restrict__ tS, int n) {
    if ((int)blockIdx.x < nfb) {
        int e = blockIdx.x * 256 + threadIdx.x;
        if (e >= E) return;
        int d = dst[e];
        int pos = atomicAdd(&cursor[d], 1);
        col[pos] = src[e];
        return;
    }
    const int row0 = ((int)blockIdx.x - nfb) * 64;
    const int tid = threadIdx.x;
    const int w = tid >> 6, lane = tid & 63;
    const int l16 = lane & 15, quad = lane >> 4;
    const int Arow = row0 + w * 16 + l16;
    f32x4 acc[8] = {};
    #pragma unroll
    for (int kk = 0; kk < 4; ++kk) {
        half8 af;
        if (Arow < n) {
            const float* ap = x + (size_t)Arow * H + kk * 32 + quad * 8;
            float4 a0 = ((const float4*)ap)[0];
            float4 a1 = ((const float4*)ap)[1];
            af[0] = (_Float16)a0.x; af[1] = (_Float16)a0.y;
            af[2] = (_Float16)a0.z; af[3] = (_Float16)a0.w;
            af[4] = (_Float16)a1.x; af[5] = (_Float16)a1.y;
            af[6] = (_Float16)a1.z; af[7] = (_Float16)a1.w;
        } else {
            #pragma unroll
            for (int j = 0; j < 8; ++j) af[j] = (_Float16)0.0f;
        }
        #pragma unroll
        for (int nt = 0; nt < 8; ++nt) {
            half8 bf = *((const half8*)(Wt1 + (nt * 16 + l16) * H + kk * 32 + quad * 8));
            acc[nt] = __builtin_amdgcn_mfma_f32_16x16x32_f16(af, bf, acc[nt], 0, 0, 0);
        }
    }
    #pragma unroll
    for (int r = 0; r < 4; ++r) {
        int R = row0 + w * 16 + quad * 4 + r;
        if (R < n) {
            float sc = dinv[R];
            _Float16* crow = tS + (size_t)R * H + l16;
            #pragma unroll
            for (int nt = 0; nt < 8; ++nt)
                crow[nt * 16] = (_Float16)(acc[nt][r] * sc);
        }
    }
}

// ---------------------------------------------------------------------------
// GEMM2, LDS-free: tS2 = (h1 @ W2) * dinv[row]
__global__ __launch_bounds__(256) void k_gemm2(const _Float16* __restrict__ h1,
                                               const _Float16* __restrict__ Wt2,
                                               const float* __restrict__ dinv,
                                               _Float16* __restrict__ tS2, int n) {
    const int row0 = blockIdx.x * 64;
    const int tid = threadIdx.x;
    const int w = tid >> 6, lane = tid & 63;
    const int l16 = lane & 15, quad = lane >> 4;
    const int Arow = row0 + w * 16 + l16;
    f32x4 acc[8] = {};
    #pragma unroll
    for (int kk = 0; kk < 4; ++kk) {
        half8 af;
        if (Arow < n) {
            af = ((const half8*)(h1 + (size_t)Arow * H))[kk * 4 + quad];
        } else {
            #pragma unroll
            for (int j = 0; j < 8; ++j) af[j] = (_Float16)0.0f;
        }
        #pragma unroll
        for (int nt = 0; nt < 8; ++nt) {
            half8 bf = *((const half8*)(Wt2 + (nt * 16 + l16) * H + kk * 32 + quad * 8));
            acc[nt] = __builtin_amdgcn_mfma_f32_16x16x32_f16(af, bf, acc[nt], 0, 0, 0);
        }
    }
    #pragma unroll
    for (int r = 0; r < 4; ++r) {
        int R = row0 + w * 16 + quad * 4 + r;
        if (R < n) {
            float sc = dinv[R];
            _Float16* crow = tS2 + (size_t)R * H + l16;
            #pragma unroll
            for (int nt = 0; nt < 8; ++nt)
                crow[nt * 16] = (_Float16)(acc[nt][r] * sc);
        }
    }
}

// ---------------------------------------------------------------------------
// XCD-sliced gather core. Slice f = blockIdx%8 owns features [f*16, f*16+16);
// per-XCD working set = 100k x 32B = 3.2MB -> fits the 4MB per-XCD L2 under
// the blockIdx%8 -> XCD round-robin dispatch heuristic (perf-only; correctness
// is mapping-independent). 8-lane group per node; lane owns 2 feats (4B);
// one j-step = 8 edges x one 32B slice each (1 cache line per edge-slice).
__device__ __forceinline__ float2 gather_slice(const _Float16* __restrict__ tS,
                                               const int* __restrict__ col,
                                               int node, int e0, int end, int foff) {
    const int lane = threadIdx.x & 63;
    const int li = lane & 7;
    const int gb = lane & 56;                     // group base lane
    float ax, ay, bx = 0.f, by = 0.f;
    {
        half2v v = *((const half2v*)(tS + (size_t)node * H + foff));  // self-loop
        ax = (float)v[0]; ay = (float)v[1];
    }
    for (int c = e0; c < end; c += 8) {
        int ce = c + li;
        int cidx = (ce < end) ? col[ce] : 0;      // 0 -> safe addr, add predicated
        int m = end - c;
        #pragma unroll
        for (int j = 0; j < 8; j += 2) {
            int s0 = __shfl(cidx, gb + j);
            int s1 = __shfl(cidx, gb + j + 1);
            half2v v0 = *((const half2v*)(tS + (size_t)s0 * H + foff));
            half2v v1 = *((const half2v*)(tS + (size_t)s1 * H + foff));
            bool ok0 = (j < m), ok1 = (j + 1 < m);
            ax += ok0 ? (float)v0[0] : 0.0f;
            ay += ok0 ? (float)v0[1] : 0.0f;
            bx += ok1 ? (float)v1[0] : 0.0f;
            by += ok1 ? (float)v1[1] : 0.0f;
        }
    }
    return make_float2(ax + bx, ay + by);
}

// sliced gather layer 1: h1 slice = relu(dinv*(self+sum) + b)
__global__ __launch_bounds__(256) void k_gather1s(const _Float16* __restrict__ tS,
                                                  const int* __restrict__ rowptr,
                                                  const int* __restrict__ col,
                                                  const float* __restrict__ dinv,
                                                  const float* __restrict__ b,
                                                  _Float16* __restrict__ out, int n) {
    int f = blockIdx.x & 7;
    int node = (blockIdx.x >> 3) * 32 + (threadIdx.x >> 3);
    if (node >= n) return;
    int li = threadIdx.x & 7;
    int foff = f * 16 + li * 2;
    int e0 = rowptr[node], end = rowptr[node + 1];
    float2 a = gather_slice(tS, col, node, e0, end, foff);
    float dn = dinv[node];
    float2 bb = *((const float2*)(b + foff));
    half2v hv;
    hv[0] = (_Float16)fmaxf(dn * a.x + bb.x, 0.0f);
    hv[1] = (_Float16)fmaxf(dn * a.y + bb.y, 0.0f);
    *((half2v*)(out + (size_t)node * H + foff)) = hv;
}

// sliced gather layer 2 + pool head: per-slice partial dot into pool8[g*8+f]
__global__ __launch_bounds__(256) void k_gather2s(const _Float16* __restrict__ tS,
                                                  const int* __restrict__ rowptr,
                                                  const int* __restrict__ col,
                                                  const float* __restrict__ dinv,
                                                  const float* __restrict__ b,
                                                  const float* __restrict__ Wp,
                                                  const int* __restrict__ batch,
                                                  float* __restrict__ pool8,
                                                  float* __restrict__ cnt, int n) {
    int f = blockIdx.x & 7;
    int node = (blockIdx.x >> 3) * 32 + (threadIdx.x >> 3);
    if (node >= n) return;
    int li = threadIdx.x & 7;
    int foff = f * 16 + li * 2;
    int e0 = rowptr[node], end = rowptr[node + 1];
    float2 a = gather_slice(tS, col, node, e0, end, foff);
    float dn = dinv[node];
    float2 bb = *((const float2*)(b + foff));
    float2 wp = *((const float2*)(Wp + foff));
    float s = fmaxf(dn * a.x + bb.x, 0.0f) * wp.x +
              fmaxf(dn * a.y + bb.y, 0.0f) * wp.y;
    // reduce within the 8-lane group (masks 1,2,4 stay in-group)
    s += __shfl_xor(s, 1);
    s += __shfl_xor(s, 2);
    s += __shfl_xor(s, 4);
    if (li == 0) {
        int g = batch[node];
        atomicAdd(&pool8[g * 8 + f], s);
        if (f == 0) atomicAdd(&cnt[g], 1.0f);
    }
}

// ---------------------------------------------------------------------------
__global__ __launch_bounds__(256) void final_out_kernel(const float* __restrict__ pool8,
                                                        const float* __restrict__ cnt,
                                                        const float* __restrict__ bp,
                                                        float* __restrict__ out, int g) {
    int i = blockIdx.x * 256 + threadIdx.x;
    if (i >= g) return;
    const float* p = pool8 + i * 8;
    float s = p[0] + p[1] + p[2] + p[3] + p[4] + p[5] + p[6] + p[7];
    out[i] = s / fmaxf(cnt[i], 1.0f) + bp[0];
}

// ---------------------------------------------------------------------------
extern "C" void kernel_launch(void* const* d_in, const int* in_sizes, int n_in,
                              void* d_out, int out_size, void* d_ws, size_t ws_size,
                              hipStream_t stream) {
    const float* x     = (const float*)d_in[0];
    const int*   ei    = (const int*)d_in[1];   // [2, E]: src = ei[0:E], dst = ei[E:2E]
    const int*   batch = (const int*)d_in[2];
    const float* W1    = (const float*)d_in[3];
    const float* b1    = (const float*)d_in[4];
    const float* W2    = (const float*)d_in[5];
    const float* b2    = (const float*)d_in[6];
    const float* Wp    = (const float*)d_in[7];
    const float* bp    = (const float*)d_in[8];
    float* out = (float*)d_out;

    const int E = in_sizes[1] / 2;   // 1,600,000
    const int* src = ei;
    const int* dst = ei + E;

    // workspace layout
    const size_t BUFH = (size_t)NN * H * sizeof(_Float16);   // 25.6 MB
    const size_t NI   = 401408;                               // >= (NN+1)*4, 4KB-mult
    char* ws = (char*)d_ws;
    size_t off = 0;
    _Float16* tS   = (_Float16*)(ws + off); off += BUFH;     // GEMM1 out (fp16)
    _Float16* h1   = (_Float16*)(ws + off); off += BUFH;     // layer-1 acts (fp16)
    _Float16* tS2  = (_Float16*)(ws + off); off += BUFH;     // GEMM2 out (fp16)
    int*      deg  = (int*)     (ws + off); off += NI;
    int*   rowptr  = (int*)     (ws + off); off += NI;
    int*   cursor  = (int*)     (ws + off); off += NI;
    float*    dinv = (float*)   (ws + off); off += NI;
    int*      col  = (int*)     (ws + off); off += ((size_t)E * 4 + 4095) / 4096 * 4096;
    _Float16* Wt1  = (_Float16*)(ws + off); off += 32768;
    _Float16* Wt2  = (_Float16*)(ws + off); off += 32768;
    int*      bsum = (int*)     (ws + off); off += 4096;
    float*   pool8 = (float*)   (ws + off); off += 16384;    // [NG][8] partials
    float*    cnt  = (float*)   (ws + off); off += 2048;

    const int NB  = (NN + 255) / 256;   // 391 scan blocks
    const int NFB = (E + 255) / 256;    // 6250 fill blocks
    const int NGB = (NN + 63) / 64;     // 1563 gemm blocks
    const int NSB = ((NN + 31) / 32) * 8;  // 25000 sliced-gather blocks

    // --- weights prep + CSR build + degree norm ---
    hipMemsetAsync(deg, 0, NN * sizeof(int), stream);
    hipMemsetAsync(pool8, 0, 16384 + 2048, stream);          // pool8 + cnt
    k_wprep<<<128, 256, 0, stream>>>(W1, W2, Wt1, Wt2);
    k_hist<<<NFB, 256, 0, stream>>>(dst, deg, E);
    k_scan_block<<<NB, 256, 0, stream>>>(deg, rowptr, bsum, NN);
    k_scan_top<<<1, 512, 0, stream>>>(bsum, NB);
    k_scan_fin<<<NB, 256, 0, stream>>>(rowptr, bsum, deg, cursor, dinv, NN, E);

    // --- fill CSR  ∥  GEMM1 (one dispatch, disjoint block ranges) ---
    k_fill_gemm1<<<NFB + NGB, 256, 0, stream>>>(src, dst, cursor, col, E, NFB,
                                                x, Wt1, dinv, tS, NN);

    // --- layer 1: XCD-sliced gather, then LDS-free MFMA GEMM2 ---
    k_gather1s<<<NSB, 256, 0, stream>>>(tS, rowptr, col, dinv, b1, h1, NN);
    k_gemm2<<<NGB, 256, 0, stream>>>(h1, Wt2, dinv, tS2, NN);

    // --- layer 2: XCD-sliced gather + pool head ---
    k_gather2s<<<NSB, 256, 0, stream>>>(tS2, rowptr, col, dinv, b2, Wp,
                                        batch, pool8, cnt, NN);

    // --- head ---
    final_out_kernel<<<(NG + 255) / 256, 256, 0, stream>>>(pool8, cnt, bp, out, NG);
}

// Round 12
// 721.668 us; speedup vs baseline: 2.0119x; 2.0119x over previous
//
#include <hip/hip_runtime.h>
#include <hip/hip_bf16.h>

// Problem constants (match reference)
#define NN 100000
#define NG 512
#define H  128

typedef _Float16 half8 __attribute__((ext_vector_type(8)));
typedef float f32x4 __attribute__((ext_vector_type(4)));

// ---------------------------------------------------------------------------
// CSR build: histogram of dst
__global__ __launch_bounds__(256) void k_hist(const int* __restrict__ dst,
                                              int* __restrict__ deg, int E) {
    int e = blockIdx.x * 256 + threadIdx.x;
    if (e < E) atomicAdd(&deg[dst[e]], 1);
}

// per-block exclusive scan (256 elems), partial sums to bsum
__global__ __launch_bounds__(256) void k_scan_block(const int* __restrict__ deg,
                                                    int* __restrict__ rowptr,
                                                    int* __restrict__ bsum, int n) {
    __shared__ int s[256];
    int tid = threadIdx.x;
    int i = blockIdx.x * 256 + tid;
    int v = (i < n) ? deg[i] : 0;
    s[tid] = v;
    __syncthreads();
    #pragma unroll
    for (int off = 1; off < 256; off <<= 1) {
        int t = (tid >= off) ? s[tid - off] : 0;
        __syncthreads();
        s[tid] += t;
        __syncthreads();
    }
    if (i < n) rowptr[i] = s[tid] - v;            // exclusive within block
    if (tid == 255) bsum[blockIdx.x] = s[255];    // block total
}

// scan of block sums (nb <= 512), single block
__global__ __launch_bounds__(512) void k_scan_top(int* __restrict__ bsum, int nb) {
    __shared__ int s[512];
    int tid = threadIdx.x;
    int v = (tid < nb) ? bsum[tid] : 0;
    s[tid] = v;
    __syncthreads();
    #pragma unroll
    for (int off = 1; off < 512; off <<= 1) {
        int t = (tid >= off) ? s[tid - off] : 0;
        __syncthreads();
        s[tid] += t;
        __syncthreads();
    }
    if (tid < nb) bsum[tid] = s[tid] - v;         // exclusive
}

// finalize: rowptr += block offset; cursor = rowptr; dinv = rsqrt(deg+1)
__global__ __launch_bounds__(256) void k_scan_fin(int* __restrict__ rowptr,
                                                  const int* __restrict__ bsum,
                                                  const int* __restrict__ deg,
                                                  int* __restrict__ cursor,
                                                  float* __restrict__ dinv,
                                                  int n, int E) {
    int i = blockIdx.x * 256 + threadIdx.x;
    if (i >= n) return;
    int r = rowptr[i] + bsum[i >> 8];
    rowptr[i] = r;
    cursor[i] = r;
    dinv[i] = rsqrtf((float)deg[i] + 1.0f);       // +1 self-loop; always > 0
    if (i == 0) rowptr[n] = E;
}

// ---------------------------------------------------------------------------
// transpose + fp16-convert both weights: Wt[n*128+k] = (half)W[k*128+n]
__global__ __launch_bounds__(256) void k_wprep(const float* __restrict__ W1,
                                               const float* __restrict__ W2,
                                               _Float16* __restrict__ Wt1,
                                               _Float16* __restrict__ Wt2) {
    int bb = blockIdx.x;
    const float* W = (bb < 64) ? W1 : W2;
    _Float16* Wt = (bb < 64) ? Wt1 : Wt2;
    int i = (bb & 63) * 256 + threadIdx.x;        // 0..16383
    int k = i >> 7, n = i & 127;
    Wt[n * 128 + k] = (_Float16)W[i];
}

// ---------------------------------------------------------------------------
// Fused: blocks [0,nfb) fill CSR col; blocks [nfb,..) do GEMM1
// (tS = (x@W1)*dinv[row], fp16 out). LDS-free MFMA GEMM.
// MFMA layouts (verified m89/m120): A[m=l16][k=quad*8+j]; B[n=l16][k=quad*8+j];
// C col=l16, row=quad*4+reg.
__global__ __launch_bounds__(256) void k_fill_gemm1(
        const int* __restrict__ src, const int* __restrict__ dst,
        int* __restrict__ cursor, int* __restrict__ col, int E, int nfb,
        const float* __restrict__ x, const _Float16* __restrict__ Wt1,
        const float* __restrict__ dinv, _Float16* __restrict__ tS, int n) {
    if ((int)blockIdx.x < nfb) {
        int e = blockIdx.x * 256 + threadIdx.x;
        if (e >= E) return;
        int d = dst[e];
        int pos = atomicAdd(&cursor[d], 1);
        col[pos] = src[e];
        return;
    }
    const int row0 = ((int)blockIdx.x - nfb) * 64;
    const int tid = threadIdx.x;
    const int w = tid >> 6, lane = tid & 63;
    const int l16 = lane & 15, quad = lane >> 4;
    const int Arow = row0 + w * 16 + l16;
    f32x4 acc[8] = {};
    #pragma unroll
    for (int kk = 0; kk < 4; ++kk) {
        half8 af;
        if (Arow < n) {
            const float* ap = x + (size_t)Arow * H + kk * 32 + quad * 8;
            float4 a0 = ((const float4*)ap)[0];
            float4 a1 = ((const float4*)ap)[1];
            af[0] = (_Float16)a0.x; af[1] = (_Float16)a0.y;
            af[2] = (_Float16)a0.z; af[3] = (_Float16)a0.w;
            af[4] = (_Float16)a1.x; af[5] = (_Float16)a1.y;
            af[6] = (_Float16)a1.z; af[7] = (_Float16)a1.w;
        } else {
            #pragma unroll
            for (int j = 0; j < 8; ++j) af[j] = (_Float16)0.0f;
        }
        #pragma unroll
        for (int nt = 0; nt < 8; ++nt) {
            half8 bf = *((const half8*)(Wt1 + (nt * 16 + l16) * H + kk * 32 + quad * 8));
            acc[nt] = __builtin_amdgcn_mfma_f32_16x16x32_f16(af, bf, acc[nt], 0, 0, 0);
        }
    }
    #pragma unroll
    for (int r = 0; r < 4; ++r) {
        int R = row0 + w * 16 + quad * 4 + r;
        if (R < n) {
            float sc = dinv[R];
            _Float16* crow = tS + (size_t)R * H + l16;
            #pragma unroll
            for (int nt = 0; nt < 8; ++nt)
                crow[nt * 16] = (_Float16)(acc[nt][r] * sc);
        }
    }
}

// ---------------------------------------------------------------------------
// GEMM2, LDS-free: tS2 = (h1 @ W2) * dinv[row]
__global__ __launch_bounds__(256) void k_gemm2(const _Float16* __restrict__ h1,
                                               const _Float16* __restrict__ Wt2,
                                               const float* __restrict__ dinv,
                                               _Float16* __restrict__ tS2, int n) {
    const int row0 = blockIdx.x * 64;
    const int tid = threadIdx.x;
    const int w = tid >> 6, lane = tid & 63;
    const int l16 = lane & 15, quad = lane >> 4;
    const int Arow = row0 + w * 16 + l16;
    f32x4 acc[8] = {};
    #pragma unroll
    for (int kk = 0; kk < 4; ++kk) {
        half8 af;
        if (Arow < n) {
            af = ((const half8*)(h1 + (size_t)Arow * H))[kk * 4 + quad];
        } else {
            #pragma unroll
            for (int j = 0; j < 8; ++j) af[j] = (_Float16)0.0f;
        }
        #pragma unroll
        for (int nt = 0; nt < 8; ++nt) {
            half8 bf = *((const half8*)(Wt2 + (nt * 16 + l16) * H + kk * 32 + quad * 8));
            acc[nt] = __builtin_amdgcn_mfma_f32_16x16x32_f16(af, bf, acc[nt], 0, 0, 0);
        }
    }
    #pragma unroll
    for (int r = 0; r < 4; ++r) {
        int R = row0 + w * 16 + quad * 4 + r;
        if (R < n) {
            float sc = dinv[R];
            _Float16* crow = tS2 + (size_t)R * H + l16;
            #pragma unroll
            for (int nt = 0; nt < 8; ++nt)
                crow[nt * 16] = (_Float16)(acc[nt][r] * sc);
        }
    }
}

// ---------------------------------------------------------------------------
// 16B row-fragment load that BYPASSES L1: agent-scope relaxed atomic loads
// lower to global_load_dwordx2 ... sc0 on gfx950, which skips the per-CU L1
// (TCP) and its miss-queue — the suspected serializer for the random gather
// stream — and goes straight to L2. Two 8B loads per 16B fragment.
__device__ __forceinline__ half8 ld_row16_nol1(const _Float16* p) {
    union { unsigned long long u[2]; half8 h; } t;
    const unsigned long long* q = (const unsigned long long*)p;
    t.u[0] = __hip_atomic_load(q,     __ATOMIC_RELAXED, __HIP_MEMORY_SCOPE_AGENT);
    t.u[1] = __hip_atomic_load(q + 1, __ATOMIC_RELAXED, __HIP_MEMORY_SCOPE_AGENT);
    return t.h;
}

// Gather core, fp16 rows (256B). One wave per node; quarter-wave q handles
// edge slot 4g+q; lane loads 16B (8 halves) of the row => one 64-lane load
// pair fetches FOUR rows. col indices bulk-loaded 64 at a time, broadcast by
// shfl. fp32 accumulate; after xor-16/32 all lanes hold feats l16*8..+7.
__device__ __forceinline__ void gather_rows_h(const _Float16* __restrict__ tS,
                                              const int* __restrict__ col,
                                              int node, int e0, int end,
                                              float acc[8]) {
    const int lane = threadIdx.x & 63;
    const int q = lane >> 4;
    const int l16 = lane & 15;
    float a0[8] = {}, a1[8] = {};
    if (q == 0) {                                   // self-loop row (normal load)
        half8 v = ((const half8*)tS)[(size_t)node * 16 + l16];
        #pragma unroll
        for (int i = 0; i < 8; ++i) a0[i] = (float)v[i];
    }
    for (int base = e0; base < end; base += 64) {
        int ce = base + lane;
        int cidx = (ce < end) ? col[ce] : 0;
        int m = min(64, end - base);
        int nf = m >> 2;                            // full groups of 4 edges
        int g = 0;
        for (; g + 2 <= nf; g += 2) {
            int s0 = __shfl(cidx, 4 * g + q);
            int s1 = __shfl(cidx, 4 * g + 4 + q);
            half8 v0 = ld_row16_nol1(tS + (size_t)s0 * H + l16 * 8);
            half8 v1 = ld_row16_nol1(tS + (size_t)s1 * H + l16 * 8);
            #pragma unroll
            for (int i = 0; i < 8; ++i) {
                a0[i] += (float)v0[i];
                a1[i] += (float)v1[i];
            }
        }
        if (g < nf) {
            int s0 = __shfl(cidx, 4 * g + q);
            half8 v0 = ld_row16_nol1(tS + (size_t)s0 * H + l16 * 8);
            #pragma unroll
            for (int i = 0; i < 8; ++i) a0[i] += (float)v0[i];
        }
        int tail = m & 3;
        if (tail) {
            int s = __shfl(cidx, 4 * nf + q);       // all lanes active here
            if (q < tail) {
                half8 v = ld_row16_nol1(tS + (size_t)s * H + l16 * 8);
                #pragma unroll
                for (int i = 0; i < 8; ++i) a0[i] += (float)v[i];
            }
        }
    }
    #pragma unroll
    for (int i = 0; i < 8; ++i) {
        float t = a0[i] + a1[i];
        t += __shfl_xor(t, 16);
        t += __shfl_xor(t, 32);
        acc[i] = t;
    }
}

// gather layer 1: out (fp16) = relu(dinv[n]*(tS[n] + sum in-edges) + b)
__global__ __launch_bounds__(256) void k_gather1(const _Float16* __restrict__ tS,
                                                 const int* __restrict__ rowptr,
                                                 const int* __restrict__ col,
                                                 const float* __restrict__ dinv,
                                                 const float* __restrict__ b,
                                                 _Float16* __restrict__ out, int n) {
    int node = blockIdx.x * 4 + (threadIdx.x >> 6);
    int lane = threadIdx.x & 63;
    int q = lane >> 4, l16 = lane & 15;
    if (node >= n) return;
    int e0 = rowptr[node], end = rowptr[node + 1];
    float acc[8];
    gather_rows_h(tS, col, node, e0, end, acc);
    if (q == 0) {
        float dn = dinv[node];
        const float4* b4 = (const float4*)b;
        float4 bb0 = b4[2 * l16], bb1 = b4[2 * l16 + 1];
        half8 hv;
        hv[0] = (_Float16)fmaxf(dn * acc[0] + bb0.x, 0.0f);
        hv[1] = (_Float16)fmaxf(dn * acc[1] + bb0.y, 0.0f);
        hv[2] = (_Float16)fmaxf(dn * acc[2] + bb0.z, 0.0f);
        hv[3] = (_Float16)fmaxf(dn * acc[3] + bb0.w, 0.0f);
        hv[4] = (_Float16)fmaxf(dn * acc[4] + bb1.x, 0.0f);
        hv[5] = (_Float16)fmaxf(dn * acc[5] + bb1.y, 0.0f);
        hv[6] = (_Float16)fmaxf(dn * acc[6] + bb1.z, 0.0f);
        hv[7] = (_Float16)fmaxf(dn * acc[7] + bb1.w, 0.0f);
        ((half8*)out)[(size_t)node * 16 + l16] = hv;
    }
}

// gather layer 2 fused with pool head: v = relu(...); pool[batch[n]] += dot(v, Wp)
__global__ __launch_bounds__(256) void k_gather2(const _Float16* __restrict__ tS,
                                                 const int* __restrict__ rowptr,
                                                 const int* __restrict__ col,
                                                 const float* __restrict__ dinv,
                                                 const float* __restrict__ b,
                                                 const float* __restrict__ Wp,
                                                 const int* __restrict__ batch,
                                                 float* __restrict__ pool,
                                                 float* __restrict__ cnt, int n) {
    int node = blockIdx.x * 4 + (threadIdx.x >> 6);
    int lane = threadIdx.x & 63;
    int l16 = lane & 15;
    if (node >= n) return;
    int e0 = rowptr[node], end = rowptr[node + 1];
    float acc[8];
    gather_rows_h(tS, col, node, e0, end, acc);
    float dn = dinv[node];
    const float4* b4 = (const float4*)b;
    const float4* w4 = (const float4*)Wp;
    float4 bb0 = b4[2 * l16], bb1 = b4[2 * l16 + 1];
    float4 wp0 = w4[2 * l16], wp1 = w4[2 * l16 + 1];
    float s = fmaxf(dn * acc[0] + bb0.x, 0.0f) * wp0.x +
              fmaxf(dn * acc[1] + bb0.y, 0.0f) * wp0.y +
              fmaxf(dn * acc[2] + bb0.z, 0.0f) * wp0.z +
              fmaxf(dn * acc[3] + bb0.w, 0.0f) * wp0.w +
              fmaxf(dn * acc[4] + bb1.x, 0.0f) * wp1.x +
              fmaxf(dn * acc[5] + bb1.y, 0.0f) * wp1.y +
              fmaxf(dn * acc[6] + bb1.z, 0.0f) * wp1.z +
              fmaxf(dn * acc[7] + bb1.w, 0.0f) * wp1.w;
    s += __shfl_xor(s, 1);
    s += __shfl_xor(s, 2);
    s += __shfl_xor(s, 4);
    s += __shfl_xor(s, 8);
    if (lane == 0) {
        int g = batch[node];
        atomicAdd(&pool[g], s);
        atomicAdd(&cnt[g], 1.0f);
    }
}

// ---------------------------------------------------------------------------
__global__ __launch_bounds__(256) void final_out_kernel(const float* __restrict__ pool,
                                                        const float* __restrict__ cnt,
                                                        const float* __restrict__ bp,
                                                        float* __restrict__ out, int g) {
    int i = blockIdx.x * 256 + threadIdx.x;
    if (i < g) out[i] = pool[i] / fmaxf(cnt[i], 1.0f) + bp[0];
}

// ---------------------------------------------------------------------------
extern "C" void kernel_launch(void* const* d_in, const int* in_sizes, int n_in,
                              void* d_out, int out_size, void* d_ws, size_t ws_size,
                              hipStream_t stream) {
    const float* x     = (const float*)d_in[0];
    const int*   ei    = (const int*)d_in[1];   // [2, E]: src = ei[0:E], dst = ei[E:2E]
    const int*   batch = (const int*)d_in[2];
    const float* W1    = (const float*)d_in[3];
    const float* b1    = (const float*)d_in[4];
    const float* W2    = (const float*)d_in[5];
    const float* b2    = (const float*)d_in[6];
    const float* Wp    = (const float*)d_in[7];
    const float* bp    = (const float*)d_in[8];
    float* out = (float*)d_out;

    const int E = in_sizes[1] / 2;   // 1,600,000
    const int* src = ei;
    const int* dst = ei + E;

    // workspace layout
    const size_t BUFH = (size_t)NN * H * sizeof(_Float16);   // 25.6 MB
    const size_t NI   = 401408;                               // >= (NN+1)*4, 4KB-mult
    char* ws = (char*)d_ws;
    size_t off = 0;
    _Float16* tS   = (_Float16*)(ws + off); off += BUFH;     // GEMM1 out (fp16)
    _Float16* h1   = (_Float16*)(ws + off); off += BUFH;     // layer-1 acts (fp16)
    _Float16* tS2  = (_Float16*)(ws + off); off += BUFH;     // GEMM2 out (fp16)
    int*      deg  = (int*)     (ws + off); off += NI;
    int*   rowptr  = (int*)     (ws + off); off += NI;
    int*   cursor  = (int*)     (ws + off); off += NI;
    float*    dinv = (float*)   (ws + off); off += NI;
    int*      col  = (int*)     (ws + off); off += ((size_t)E * 4 + 4095) / 4096 * 4096;
    _Float16* Wt1  = (_Float16*)(ws + off); off += 32768;
    _Float16* Wt2  = (_Float16*)(ws + off); off += 32768;
    int*      bsum = (int*)     (ws + off); off += 4096;
    float*    pool = (float*)   (ws + off); off += 2048;
    float*    cnt  = (float*)   (ws + off); off += 2048;

    const int NB  = (NN + 255) / 256;   // 391 scan blocks
    const int NFB = (E + 255) / 256;    // 6250 fill blocks
    const int NGB = (NN + 63) / 64;     // 1563 gemm blocks

    // --- weights prep + CSR build + degree norm ---
    hipMemsetAsync(deg, 0, NN * sizeof(int), stream);
    hipMemsetAsync(pool, 0, 4096, stream);                   // pool + cnt
    k_wprep<<<128, 256, 0, stream>>>(W1, W2, Wt1, Wt2);
    k_hist<<<NFB, 256, 0, stream>>>(dst, deg, E);
    k_scan_block<<<NB, 256, 0, stream>>>(deg, rowptr, bsum, NN);
    k_scan_top<<<1, 512, 0, stream>>>(bsum, NB);
    k_scan_fin<<<NB, 256, 0, stream>>>(rowptr, bsum, deg, cursor, dinv, NN, E);

    // --- fill CSR  ∥  GEMM1 (one dispatch, disjoint block ranges) ---
    k_fill_gemm1<<<NFB + NGB, 256, 0, stream>>>(src, dst, cursor, col, E, NFB,
                                                x, Wt1, dinv, tS, NN);

    // --- layer 1: gather (wave/node) then LDS-free MFMA GEMM2 ---
    k_gather1<<<(NN + 3) / 4, 256, 0, stream>>>(tS, rowptr, col, dinv, b1, h1, NN);
    k_gemm2<<<NGB, 256, 0, stream>>>(h1, Wt2, dinv, tS2, NN);

    // --- layer 2 gather + pool head ---
    k_gather2<<<(NN + 3) / 4, 256, 0, stream>>>(tS2, rowptr, col, dinv, b2, Wp,
                                                batch, pool, cnt, NN);

    // --- head ---
    final_out_kernel<<<(NG + 255) / 256, 256, 0, stream>>>(pool, cnt, bp, out, NG);
}

// Round 13
// 660.783 us; speedup vs baseline: 2.1972x; 1.0921x over previous
//
#include <hip/hip_runtime.h>
#include <hip/hip_bf16.h>

// Problem constants (match reference)
#define NN 100000
#define NG 512
#define H  128

typedef _Float16 half8 __attribute__((ext_vector_type(8)));
typedef float f32x4 __attribute__((ext_vector_type(4)));

// ---------------------------------------------------------------------------
// Merged: blocks [0,128) transpose+fp16-convert W1/W2; blocks [128,..) dst hist
__global__ __launch_bounds__(256) void k_wprep_hist(const float* __restrict__ W1,
                                                    const float* __restrict__ W2,
                                                    _Float16* __restrict__ Wt1,
                                                    _Float16* __restrict__ Wt2,
                                                    const int* __restrict__ dst,
                                                    int* __restrict__ deg, int E) {
    int bb = blockIdx.x;
    if (bb < 128) {
        const float* W = (bb < 64) ? W1 : W2;
        _Float16* Wt = (bb < 64) ? Wt1 : Wt2;
        int i = (bb & 63) * 256 + threadIdx.x;    // 0..16383
        int k = i >> 7, n = i & 127;
        Wt[n * 128 + k] = (_Float16)W[i];
        return;
    }
    int e = (bb - 128) * 256 + threadIdx.x;
    if (e < E) atomicAdd(&deg[dst[e]], 1);
}

// per-block exclusive scan (256 elems), partial sums to bsum
__global__ __launch_bounds__(256) void k_scan_block(const int* __restrict__ deg,
                                                    int* __restrict__ rowptr,
                                                    int* __restrict__ bsum, int n) {
    __shared__ int s[256];
    int tid = threadIdx.x;
    int i = blockIdx.x * 256 + tid;
    int v = (i < n) ? deg[i] : 0;
    s[tid] = v;
    __syncthreads();
    #pragma unroll
    for (int off = 1; off < 256; off <<= 1) {
        int t = (tid >= off) ? s[tid - off] : 0;
        __syncthreads();
        s[tid] += t;
        __syncthreads();
    }
    if (i < n) rowptr[i] = s[tid] - v;            // exclusive within block
    if (tid == 255) bsum[blockIdx.x] = s[255];    // block total
}

// scan of block sums (nb <= 512), single block
__global__ __launch_bounds__(512) void k_scan_top(int* __restrict__ bsum, int nb) {
    __shared__ int s[512];
    int tid = threadIdx.x;
    int v = (tid < nb) ? bsum[tid] : 0;
    s[tid] = v;
    __syncthreads();
    #pragma unroll
    for (int off = 1; off < 512; off <<= 1) {
        int t = (tid >= off) ? s[tid - off] : 0;
        __syncthreads();
        s[tid] += t;
        __syncthreads();
    }
    if (tid < nb) bsum[tid] = s[tid] - v;         // exclusive
}

// finalize: rowptr += block offset; cursor = rowptr; dinv = rsqrt(deg+1)
__global__ __launch_bounds__(256) void k_scan_fin(int* __restrict__ rowptr,
                                                  const int* __restrict__ bsum,
                                                  const int* __restrict__ deg,
                                                  int* __restrict__ cursor,
                                                  float* __restrict__ dinv,
                                                  int n, int E) {
    int i = blockIdx.x * 256 + threadIdx.x;
    if (i >= n) return;
    int r = rowptr[i] + bsum[i >> 8];
    rowptr[i] = r;
    cursor[i] = r;
    dinv[i] = rsqrtf((float)deg[i] + 1.0f);       // +1 self-loop; always > 0
    if (i == 0) rowptr[n] = E;
}

// ---------------------------------------------------------------------------
// Fused: blocks [0,nfb) fill CSR col; blocks [nfb,..) do GEMM1
// (tS = (x@W1)*dinv[row], fp16 out). LDS-free MFMA GEMM.
// MFMA layouts (verified m89/m120): A[m=l16][k=quad*8+j]; B[n=l16][k=quad*8+j];
// C col=l16, row=quad*4+reg.
__global__ __launch_bounds__(256) void k_fill_gemm1(
        const int* __restrict__ src, const int* __restrict__ dst,
        int* __restrict__ cursor, int* __restrict__ col, int E, int nfb,
        const float* __restrict__ x, const _Float16* __restrict__ Wt1,
        const float* __restrict__ dinv, _Float16* __restrict__ tS, int n) {
    if ((int)blockIdx.x < nfb) {
        int e = blockIdx.x * 256 + threadIdx.x;
        if (e >= E) return;
        int d = dst[e];
        int pos = atomicAdd(&cursor[d], 1);
        col[pos] = src[e];
        return;
    }
    const int row0 = ((int)blockIdx.x - nfb) * 64;
    const int tid = threadIdx.x;
    const int w = tid >> 6, lane = tid & 63;
    const int l16 = lane & 15, quad = lane >> 4;
    const int Arow = row0 + w * 16 + l16;
    f32x4 acc[8] = {};
    #pragma unroll
    for (int kk = 0; kk < 4; ++kk) {
        half8 af;
        if (Arow < n) {
            const float* ap = x + (size_t)Arow * H + kk * 32 + quad * 8;
            float4 a0 = ((const float4*)ap)[0];
            float4 a1 = ((const float4*)ap)[1];
            af[0] = (_Float16)a0.x; af[1] = (_Float16)a0.y;
            af[2] = (_Float16)a0.z; af[3] = (_Float16)a0.w;
            af[4] = (_Float16)a1.x; af[5] = (_Float16)a1.y;
            af[6] = (_Float16)a1.z; af[7] = (_Float16)a1.w;
        } else {
            #pragma unroll
            for (int j = 0; j < 8; ++j) af[j] = (_Float16)0.0f;
        }
        #pragma unroll
        for (int nt = 0; nt < 8; ++nt) {
            half8 bf = *((const half8*)(Wt1 + (nt * 16 + l16) * H + kk * 32 + quad * 8));
            acc[nt] = __builtin_amdgcn_mfma_f32_16x16x32_f16(af, bf, acc[nt], 0, 0, 0);
        }
    }
    #pragma unroll
    for (int r = 0; r < 4; ++r) {
        int R = row0 + w * 16 + quad * 4 + r;
        if (R < n) {
            float sc = dinv[R];
            _Float16* crow = tS + (size_t)R * H + l16;
            #pragma unroll
            for (int nt = 0; nt < 8; ++nt)
                crow[nt * 16] = (_Float16)(acc[nt][r] * sc);
        }
    }
}

// ---------------------------------------------------------------------------
// GEMM2, LDS-free: tS2 = (h1 @ W2) * dinv[row]
__global__ __launch_bounds__(256) void k_gemm2(const _Float16* __restrict__ h1,
                                               const _Float16* __restrict__ Wt2,
                                               const float* __restrict__ dinv,
                                               _Float16* __restrict__ tS2, int n) {
    const int row0 = blockIdx.x * 64;
    const int tid = threadIdx.x;
    const int w = tid >> 6, lane = tid & 63;
    const int l16 = lane & 15, quad = lane >> 4;
    const int Arow = row0 + w * 16 + l16;
    f32x4 acc[8] = {};
    #pragma unroll
    for (int kk = 0; kk < 4; ++kk) {
        half8 af;
        if (Arow < n) {
            af = ((const half8*)(h1 + (size_t)Arow * H))[kk * 4 + quad];
        } else {
            #pragma unroll
            for (int j = 0; j < 8; ++j) af[j] = (_Float16)0.0f;
        }
        #pragma unroll
        for (int nt = 0; nt < 8; ++nt) {
            half8 bf = *((const half8*)(Wt2 + (nt * 16 + l16) * H + kk * 32 + quad * 8));
            acc[nt] = __builtin_amdgcn_mfma_f32_16x16x32_f16(af, bf, acc[nt], 0, 0, 0);
        }
    }
    #pragma unroll
    for (int r = 0; r < 4; ++r) {
        int R = row0 + w * 16 + quad * 4 + r;
        if (R < n) {
            float sc = dinv[R];
            _Float16* crow = tS2 + (size_t)R * H + l16;
            #pragma unroll
            for (int nt = 0; nt < 8; ++nt)
                crow[nt * 16] = (_Float16)(acc[nt][r] * sc);
        }
    }
}

// ---------------------------------------------------------------------------
// 16B row-fragment load that BYPASSES L1 (agent-scope relaxed atomic ->
// global_load_dwordx2 sc0). Used ONLY in gather2 (no store stream there);
// measured −4% in gather2, regression in store-heavy gather1 (r12).
__device__ __forceinline__ half8 ld_row16_nol1(const _Float16* p) {
    union { unsigned long long u[2]; half8 h; } t;
    const unsigned long long* q = (const unsigned long long*)p;
    t.u[0] = __hip_atomic_load(q,     __ATOMIC_RELAXED, __HIP_MEMORY_SCOPE_AGENT);
    t.u[1] = __hip_atomic_load(q + 1, __ATOMIC_RELAXED, __HIP_MEMORY_SCOPE_AGENT);
    return t.h;
}

// Gather core, fp16 rows (256B). One wave per node; quarter-wave q handles
// edge slot 4g+q; lane loads 16B (8 halves) of the row. col indices
// bulk-loaded 64 at a time, broadcast by shfl. fp32 accumulate; after
// xor-16/32 all lanes hold the full sum for feats l16*8..+7.
template <bool NOL1>
__device__ __forceinline__ void gather_rows_h(const _Float16* __restrict__ tS,
                                              const int* __restrict__ col,
                                              int node, int e0, int end,
                                              float acc[8]) {
    const int lane = threadIdx.x & 63;
    const int q = lane >> 4;
    const int l16 = lane & 15;
    float a0[8] = {}, a1[8] = {};
    if (q == 0) {                                   // self-loop row (cached load)
        half8 v = ((const half8*)tS)[(size_t)node * 16 + l16];
        #pragma unroll
        for (int i = 0; i < 8; ++i) a0[i] = (float)v[i];
    }
    for (int base = e0; base < end; base += 64) {
        int ce = base + lane;
        int cidx = (ce < end) ? col[ce] : 0;
        int m = min(64, end - base);
        int nf = m >> 2;                            // full groups of 4 edges
        int g = 0;
        for (; g + 2 <= nf; g += 2) {
            int s0 = __shfl(cidx, 4 * g + q);
            int s1 = __shfl(cidx, 4 * g + 4 + q);
            half8 v0, v1;
            if (NOL1) {
                v0 = ld_row16_nol1(tS + (size_t)s0 * H + l16 * 8);
                v1 = ld_row16_nol1(tS + (size_t)s1 * H + l16 * 8);
            } else {
                v0 = ((const half8*)tS)[(size_t)s0 * 16 + l16];
                v1 = ((const half8*)tS)[(size_t)s1 * 16 + l16];
            }
            #pragma unroll
            for (int i = 0; i < 8; ++i) {
                a0[i] += (float)v0[i];
                a1[i] += (float)v1[i];
            }
        }
        if (g < nf) {
            int s0 = __shfl(cidx, 4 * g + q);
            half8 v0 = NOL1 ? ld_row16_nol1(tS + (size_t)s0 * H + l16 * 8)
                            : ((const half8*)tS)[(size_t)s0 * 16 + l16];
            #pragma unroll
            for (int i = 0; i < 8; ++i) a0[i] += (float)v0[i];
        }
        int tail = m & 3;
        if (tail) {
            int s = __shfl(cidx, 4 * nf + q);       // all lanes active here
            if (q < tail) {
                half8 v = NOL1 ? ld_row16_nol1(tS + (size_t)s * H + l16 * 8)
                               : ((const half8*)tS)[(size_t)s * 16 + l16];
                #pragma unroll
                for (int i = 0; i < 8; ++i) a0[i] += (float)v[i];
            }
        }
    }
    #pragma unroll
    for (int i = 0; i < 8; ++i) {
        float t = a0[i] + a1[i];
        t += __shfl_xor(t, 16);
        t += __shfl_xor(t, 32);
        acc[i] = t;
    }
}

// gather layer 1: out (fp16) = relu(dinv[n]*(tS[n] + sum in-edges) + b)
__global__ __launch_bounds__(256) void k_gather1(const _Float16* __restrict__ tS,
                                                 const int* __restrict__ rowptr,
                                                 const int* __restrict__ col,
                                                 const float* __restrict__ dinv,
                                                 const float* __restrict__ b,
                                                 _Float16* __restrict__ out, int n) {
    int node = blockIdx.x * 4 + (threadIdx.x >> 6);
    int lane = threadIdx.x & 63;
    int q = lane >> 4, l16 = lane & 15;
    if (node >= n) return;
    int e0 = rowptr[node], end = rowptr[node + 1];
    float acc[8];
    gather_rows_h<false>(tS, col, node, e0, end, acc);
    if (q == 0) {
        float dn = dinv[node];
        const float4* b4 = (const float4*)b;
        float4 bb0 = b4[2 * l16], bb1 = b4[2 * l16 + 1];
        half8 hv;
        hv[0] = (_Float16)fmaxf(dn * acc[0] + bb0.x, 0.0f);
        hv[1] = (_Float16)fmaxf(dn * acc[1] + bb0.y, 0.0f);
        hv[2] = (_Float16)fmaxf(dn * acc[2] + bb0.z, 0.0f);
        hv[3] = (_Float16)fmaxf(dn * acc[3] + bb0.w, 0.0f);
        hv[4] = (_Float16)fmaxf(dn * acc[4] + bb1.x, 0.0f);
        hv[5] = (_Float16)fmaxf(dn * acc[5] + bb1.y, 0.0f);
        hv[6] = (_Float16)fmaxf(dn * acc[6] + bb1.z, 0.0f);
        hv[7] = (_Float16)fmaxf(dn * acc[7] + bb1.w, 0.0f);
        ((half8*)out)[(size_t)node * 16 + l16] = hv;
    }
}

// gather layer 2 fused with pool head: v = relu(...); pool[batch[n]] += dot(v, Wp)
__global__ __launch_bounds__(256) void k_gather2(const _Float16* __restrict__ tS,
                                                 const int* __restrict__ rowptr,
                                                 const int* __restrict__ col,
                                                 const float* __restrict__ dinv,
                                                 const float* __restrict__ b,
                                                 const float* __restrict__ Wp,
                                                 const int* __restrict__ batch,
                                                 float* __restrict__ pool,
                                                 float* __restrict__ cnt, int n) {
    int node = blockIdx.x * 4 + (threadIdx.x >> 6);
    int lane = threadIdx.x & 63;
    int l16 = lane & 15;
    if (node >= n) return;
    int e0 = rowptr[node], end = rowptr[node + 1];
    float acc[8];
    gather_rows_h<true>(tS, col, node, e0, end, acc);
    float dn = dinv[node];
    const float4* b4 = (const float4*)b;
    const float4* w4 = (const float4*)Wp;
    float4 bb0 = b4[2 * l16], bb1 = b4[2 * l16 + 1];
    float4 wp0 = w4[2 * l16], wp1 = w4[2 * l16 + 1];
    float s = fmaxf(dn * acc[0] + bb0.x, 0.0f) * wp0.x +
              fmaxf(dn * acc[1] + bb0.y, 0.0f) * wp0.y +
              fmaxf(dn * acc[2] + bb0.z, 0.0f) * wp0.z +
              fmaxf(dn * acc[3] + bb0.w, 0.0f) * wp0.w +
              fmaxf(dn * acc[4] + bb1.x, 0.0f) * wp1.x +
              fmaxf(dn * acc[5] + bb1.y, 0.0f) * wp1.y +
              fmaxf(dn * acc[6] + bb1.z, 0.0f) * wp1.z +
              fmaxf(dn * acc[7] + bb1.w, 0.0f) * wp1.w;
    s += __shfl_xor(s, 1);
    s += __shfl_xor(s, 2);
    s += __shfl_xor(s, 4);
    s += __shfl_xor(s, 8);
    if (lane == 0) {
        int g = batch[node];
        atomicAdd(&pool[g], s);
        atomicAdd(&cnt[g], 1.0f);
    }
}

// ---------------------------------------------------------------------------
__global__ __launch_bounds__(256) void final_out_kernel(const float* __restrict__ pool,
                                                        const float* __restrict__ cnt,
                                                        const float* __restrict__ bp,
                                                        float* __restrict__ out, int g) {
    int i = blockIdx.x * 256 + threadIdx.x;
    if (i < g) out[i] = pool[i] / fmaxf(cnt[i], 1.0f) + bp[0];
}

// ---------------------------------------------------------------------------
extern "C" void kernel_launch(void* const* d_in, const int* in_sizes, int n_in,
                              void* d_out, int out_size, void* d_ws, size_t ws_size,
                              hipStream_t stream) {
    const float* x     = (const float*)d_in[0];
    const int*   ei    = (const int*)d_in[1];   // [2, E]: src = ei[0:E], dst = ei[E:2E]
    const int*   batch = (const int*)d_in[2];
    const float* W1    = (const float*)d_in[3];
    const float* b1    = (const float*)d_in[4];
    const float* W2    = (const float*)d_in[5];
    const float* b2    = (const float*)d_in[6];
    const float* Wp    = (const float*)d_in[7];
    const float* bp    = (const float*)d_in[8];
    float* out = (float*)d_out;

    const int E = in_sizes[1] / 2;   // 1,600,000
    const int* src = ei;
    const int* dst = ei + E;

    // workspace layout
    const size_t BUFH = (size_t)NN * H * sizeof(_Float16);   // 25.6 MB
    const size_t NI   = 401408;                               // >= (NN+1)*4, 4KB-mult
    char* ws = (char*)d_ws;
    size_t off = 0;
    _Float16* tS   = (_Float16*)(ws + off); off += BUFH;     // GEMM1 out (fp16)
    _Float16* h1   = (_Float16*)(ws + off); off += BUFH;     // layer-1 acts (fp16)
    _Float16* tS2  = (_Float16*)(ws + off); off += BUFH;     // GEMM2 out (fp16)
    int*      deg  = (int*)     (ws + off); off += NI;
    int*   rowptr  = (int*)     (ws + off); off += NI;
    int*   cursor  = (int*)     (ws + off); off += NI;
    float*    dinv = (float*)   (ws + off); off += NI;
    int*      col  = (int*)     (ws + off); off += ((size_t)E * 4 + 4095) / 4096 * 4096;
    _Float16* Wt1  = (_Float16*)(ws + off); off += 32768;
    _Float16* Wt2  = (_Float16*)(ws + off); off += 32768;
    int*      bsum = (int*)     (ws + off); off += 4096;
    float*    pool = (float*)   (ws + off); off += 2048;
    float*    cnt  = (float*)   (ws + off); off += 2048;

    const int NB  = (NN + 255) / 256;   // 391 scan blocks
    const int NFB = (E + 255) / 256;    // 6250 fill/hist blocks
    const int NGB = (NN + 63) / 64;     // 1563 gemm blocks

    // --- weights prep ∥ histogram (one dispatch), then scans ---
    hipMemsetAsync(deg, 0, NN * sizeof(int), stream);
    hipMemsetAsync(pool, 0, 4096, stream);                   // pool + cnt
    k_wprep_hist<<<128 + NFB, 256, 0, stream>>>(W1, W2, Wt1, Wt2, dst, deg, E);
    k_scan_block<<<NB, 256, 0, stream>>>(deg, rowptr, bsum, NN);
    k_scan_top<<<1, 512, 0, stream>>>(bsum, NB);
    k_scan_fin<<<NB, 256, 0, stream>>>(rowptr, bsum, deg, cursor, dinv, NN, E);

    // --- fill CSR  ∥  GEMM1 (one dispatch, disjoint block ranges) ---
    k_fill_gemm1<<<NFB + NGB, 256, 0, stream>>>(src, dst, cursor, col, E, NFB,
                                                x, Wt1, dinv, tS, NN);

    // --- layer 1: gather (wave/node) then LDS-free MFMA GEMM2 ---
    k_gather1<<<(NN + 3) / 4, 256, 0, stream>>>(tS, rowptr, col, dinv, b1, h1, NN);
    k_gemm2<<<NGB, 256, 0, stream>>>(h1, Wt2, dinv, tS2, NN);

    // --- layer 2 gather + pool head ---
    k_gather2<<<(NN + 3) / 4, 256, 0, stream>>>(tS2, rowptr, col, dinv, b2, Wp,
                                                batch, pool, cnt, NN);

    // --- head ---
    final_out_kernel<<<(NG + 255) / 256, 256, 0, stream>>>(pool, cnt, bp, out, NG);
}